// Round 1
// baseline (707.054 us; speedup 1.0000x reference)
//
#include <hip/hip_runtime.h>
#include <math.h>

#define BB 8
#define CH 96
#define HH 256
#define WW 256
#define PD 64      // PDIM
#define NBASE 8
#define KK 13
#define SK 3
#define HID 32

#define PLANE 65536  // 256*256

// ---------------- K1: pooled mean over H,W for first 64 channels ----------------
__global__ __launch_bounds__(256) void pool_kernel(const float* __restrict__ x,
                                                   float* __restrict__ pooled) {
    int blk = blockIdx.x;            // b*64 + c
    int b = blk >> 6, c = blk & 63;
    const float4* p4 = (const float4*)(x + (size_t)(b * CH + c) * PLANE);
    int t = threadIdx.x;
    float s = 0.f;
#pragma unroll
    for (int i = 0; i < 64; ++i) {
        float4 v = p4[t + (i << 8)];
        s += v.x + v.y + v.z + v.w;
    }
#pragma unroll
    for (int off = 32; off; off >>= 1) s += __shfl_down(s, off, 64);
    __shared__ float ls[4];
    if ((t & 63) == 0) ls[t >> 6] = s;
    __syncthreads();
    if (t == 0) pooled[blk] = (ls[0] + ls[1] + ls[2] + ls[3]) * (1.f / 65536.f);
}

// ---------------- K2: all tiny MLPs + softmaxes + kernel composition ----------------
__global__ __launch_bounds__(256) void mlp_kernel(
    const float* __restrict__ pooled, const float* __restrict__ lk_bases,
    const float* __restrict__ rw1, const float* __restrict__ rb1,
    const float* __restrict__ rw2, const float* __restrict__ rb2,
    const float* __restrict__ sw1, const float* __restrict__ sb1,
    const float* __restrict__ sw2, const float* __restrict__ sb2,
    const float* __restrict__ gw1, const float* __restrict__ gb1,
    const float* __restrict__ gw2, const float* __restrict__ gb2,
    float* __restrict__ composed, float* __restrict__ dynk,
    float* __restrict__ glk, float* __restrict__ gdyn) {
    int b = blockIdx.x;
    int t = threadIdx.x;
    __shared__ float pl[64];
    __shared__ float h[3][HID];
    __shared__ float ro[PD * NBASE];
    __shared__ float go[2 * PD];
    __shared__ float rw[PD][NBASE];

    if (t < 64) pl[t] = pooled[b * 64 + t];
    __syncthreads();

    if (t < 96) {
        int m = t >> 5, u = t & 31;
        const float* w1 = (m == 0) ? rw1 : ((m == 1) ? sw1 : gw1);
        const float* b1 = (m == 0) ? rb1 : ((m == 1) ? sb1 : gb1);
        float a = b1[u];
#pragma unroll
        for (int i = 0; i < 64; ++i) a += w1[u * 64 + i] * pl[i];
        // exact gelu: x * 0.5 * (1 + erf(x/sqrt(2)))
        h[m][u] = a * 0.5f * (1.f + erff(a * 0.70710678118654752f));
    }
    __syncthreads();

    for (int o = t; o < PD * NBASE; o += 256) {
        float a = rb2[o];
#pragma unroll
        for (int i = 0; i < HID; ++i) a += rw2[o * HID + i] * h[0][i];
        ro[o] = a;
    }
    for (int o = t; o < PD * SK * SK; o += 256) {
        float a = sb2[o];
#pragma unroll
        for (int i = 0; i < HID; ++i) a += sw2[o * HID + i] * h[1][i];
        dynk[b * PD * SK * SK + o] = a;
    }
    if (t < 2 * PD) {
        float a = gb2[t];
#pragma unroll
        for (int i = 0; i < HID; ++i) a += gw2[t * HID + i] * h[2][i];
        go[t] = a;
    }
    __syncthreads();

    if (t < 64) {
        // softmax over NB for rw
        float m = -1e30f;
#pragma unroll
        for (int n = 0; n < NBASE; ++n) m = fmaxf(m, ro[t * NBASE + n]);
        float e[NBASE], s = 0.f;
#pragma unroll
        for (int n = 0; n < NBASE; ++n) { e[n] = expf(ro[t * NBASE + n] - m); s += e[n]; }
        float inv = 1.f / s;
#pragma unroll
        for (int n = 0; n < NBASE; ++n) rw[t][n] = e[n] * inv;
        // gate softmax over the 2 experts
        float a0 = go[t], a1 = go[64 + t];
        float mm = fmaxf(a0, a1);
        float e0 = expf(a0 - mm), e1 = expf(a1 - mm);
        float gi = 1.f / (e0 + e1);
        glk[b * 64 + t] = e0 * gi;
        gdyn[b * 64 + t] = e1 * gi;
    }
    __syncthreads();

    for (int idx = t; idx < 64 * KK * KK; idx += 256) {
        int c = idx / (KK * KK);
        int j = idx - c * (KK * KK);
        float a = 0.f;
#pragma unroll
        for (int n = 0; n < NBASE; ++n) a += rw[c][n] * lk_bases[n * KK * KK + j];
        composed[(size_t)(b * 64 + c) * (KK * KK) + j] = a;
    }
}

// ---------------- K3: fused depthwise 13x13 + 3x3 + gating; writes fused into d_out y1 slots ----------------
#define TH 32
#define TW 64
#define TROWS 44     // TH + 12
#define TSTR 80      // TW + 12 padded to multiple of 4 for float4 LDS reads

__global__ __launch_bounds__(256) void conv_kernel(
    const float* __restrict__ x, const float* __restrict__ composed,
    const float* __restrict__ dynk, const float* __restrict__ glk,
    const float* __restrict__ gdyn, float* __restrict__ outp) {
    int tx = blockIdx.x;              // 32 tiles: 4 W-tiles x 8 H-tiles
    int wt = tx & 3, ht = tx >> 2;
    int c = blockIdx.y, b = blockIdx.z;
    int h0 = ht * TH, w0 = wt * TW;
    int t = threadIdx.x;

    __shared__ __align__(16) float tile[TROWS * TSTR];
    __shared__ __align__(16) float kl[13 * 16];
    __shared__ float dk[9];

    const float* xp = x + (size_t)(b * CH + c) * PLANE;
    for (int idx = t; idx < TROWS * TSTR; idx += 256) {
        int rr = idx / TSTR, cc = idx - rr * TSTR;
        int gh = h0 - 6 + rr, gw = w0 - 6 + cc;
        float v = 0.f;
        if (gh >= 0 && gh < HH && gw >= 0 && gw < WW) v = xp[gh * WW + gw];
        tile[idx] = v;
    }
    if (t < 169) {
        int dy = t / 13, dw = t - dy * 13;
        kl[dy * 16 + dw] = composed[(size_t)(b * 64 + c) * 169 + t];
    }
    if (t >= 192 && t < 201) dk[t - 192] = dynk[b * PD * 9 + c * 9 + (t - 192)];
    __syncthreads();

    int wg = t & 7;        // 8 w-groups of 8 pixels
    int r  = t >> 3;       // 32 rows
    float acc[8] = {0, 0, 0, 0, 0, 0, 0, 0};

#pragma unroll
    for (int dy = 0; dy < 13; ++dy) {
        const float* xr = &tile[(r + dy) * TSTR + wg * 8];
        float kv[16];
        *(float4*)&kv[0] = *(const float4*)&kl[dy * 16];
        *(float4*)&kv[4] = *(const float4*)&kl[dy * 16 + 4];
        *(float4*)&kv[8] = *(const float4*)&kl[dy * 16 + 8];
        kv[12] = kl[dy * 16 + 12];
        float xv[20] __attribute__((aligned(16)));
        *(float4*)&xv[0]  = *(const float4*)&xr[0];
        *(float4*)&xv[4]  = *(const float4*)&xr[4];
        *(float4*)&xv[8]  = *(const float4*)&xr[8];
        *(float4*)&xv[12] = *(const float4*)&xr[12];
        *(float4*)&xv[16] = *(const float4*)&xr[16];
#pragma unroll
        for (int dw = 0; dw < 13; ++dw)
#pragma unroll
            for (int j = 0; j < 8; ++j)
                acc[j] = fmaf(kv[dw], xv[dw + j], acc[j]);
    }

    float acc2[8] = {0, 0, 0, 0, 0, 0, 0, 0};
#pragma unroll
    for (int dy = 0; dy < 3; ++dy) {
        const float* xr = &tile[(r + 5 + dy) * TSTR + wg * 8 + 5];
        float kv0 = dk[dy * 3 + 0], kv1 = dk[dy * 3 + 1], kv2 = dk[dy * 3 + 2];
        float xv[10];
#pragma unroll
        for (int i = 0; i < 10; ++i) xv[i] = xr[i];
#pragma unroll
        for (int j = 0; j < 8; ++j) {
            float a = acc2[j];
            a = fmaf(kv0, xv[j], a);
            a = fmaf(kv1, xv[j + 1], a);
            a = fmaf(kv2, xv[j + 2], a);
            acc2[j] = a;
        }
    }

    float gl = glk[b * 64 + c], gd = gdyn[b * 64 + c];
    float* op = outp + (size_t)(b * CH + c) * PLANE + (h0 + r) * WW + (w0 + wg * 8);
    float4 o0, o1;
    o0.x = gl * acc[0] + gd * acc2[0];
    o0.y = gl * acc[1] + gd * acc2[1];
    o0.z = gl * acc[2] + gd * acc2[2];
    o0.w = gl * acc[3] + gd * acc2[3];
    o1.x = gl * acc[4] + gd * acc2[4];
    o1.y = gl * acc[5] + gd * acc2[5];
    o1.z = gl * acc[6] + gd * acc2[6];
    o1.w = gl * acc[7] + gd * acc2[7];
    *(float4*)&op[0] = o0;
    *(float4*)&op[4] = o1;
}

// ---------------- K4: 64x64 pointwise + bias + residual, in-place on d_out y1 slots ----------------
__global__ __launch_bounds__(256) void pointwise_kernel(
    const float* __restrict__ x, const float* __restrict__ fw,
    const float* __restrict__ fb, float* __restrict__ outp) {
    int b = blockIdx.y;
    int px = blockIdx.x * 256 + threadIdx.x;   // 0..65535
    const size_t bb = (size_t)b * CH * PLANE;

    float f[64];
#pragma unroll
    for (int c = 0; c < 64; ++c) f[c] = outp[bb + (size_t)c * PLANE + px];

    for (int o = 0; o < 64; ++o) {
        float a = fb[o];
#pragma unroll
        for (int c = 0; c < 64; ++c) a = fmaf(fw[o * 64 + c], f[c], a);
        outp[bb + (size_t)o * PLANE + px] = a + x[bb + (size_t)o * PLANE + px];
    }
}

// ---------------- K5: pass-through copy of channels 64..95 ----------------
__global__ __launch_bounds__(256) void copy_kernel(const float* __restrict__ x,
                                                   float* __restrict__ outp) {
    size_t i = (size_t)blockIdx.x * 256 + threadIdx.x;  // over 4,194,304 float4
    int b = (int)(i >> 19);                             // 524288 float4 per batch
    size_t off = i & 524287;
    const float4* s = (const float4*)(x + ((size_t)b * CH + 64) * PLANE) + off;
    float4* d = (float4*)(outp + ((size_t)b * CH + 64) * PLANE) + off;
    *d = *s;
}

extern "C" void kernel_launch(void* const* d_in, const int* in_sizes, int n_in,
                              void* d_out, int out_size, void* d_ws, size_t ws_size,
                              hipStream_t stream) {
    const float* x        = (const float*)d_in[0];
    const float* lk_bases = (const float*)d_in[1];
    const float* rw1      = (const float*)d_in[2];
    const float* rb1      = (const float*)d_in[3];
    const float* rw2      = (const float*)d_in[4];
    const float* rb2      = (const float*)d_in[5];
    const float* sw1      = (const float*)d_in[6];
    const float* sb1      = (const float*)d_in[7];
    const float* sw2      = (const float*)d_in[8];
    const float* sb2      = (const float*)d_in[9];
    const float* gw1      = (const float*)d_in[10];
    const float* gb1      = (const float*)d_in[11];
    const float* gw2      = (const float*)d_in[12];
    const float* gb2      = (const float*)d_in[13];
    const float* fw       = (const float*)d_in[14];
    const float* fb       = (const float*)d_in[15];
    float* outp = (float*)d_out;

    float* wsf      = (float*)d_ws;
    float* pooled   = wsf;                 // 512
    float* composed = wsf + 512;           // 86528
    float* dynk     = wsf + 87040;         // 4608
    float* glk      = wsf + 91648;         // 512
    float* gdyn     = wsf + 92160;         // 512

    pool_kernel<<<dim3(512), dim3(256), 0, stream>>>(x, pooled);
    mlp_kernel<<<dim3(8), dim3(256), 0, stream>>>(pooled, lk_bases,
        rw1, rb1, rw2, rb2, sw1, sb1, sw2, sb2, gw1, gb1, gw2, gb2,
        composed, dynk, glk, gdyn);
    conv_kernel<<<dim3(32, 64, 8), dim3(256), 0, stream>>>(x, composed, dynk, glk, gdyn, outp);
    pointwise_kernel<<<dim3(256, 8), dim3(256), 0, stream>>>(x, fw, fb, outp);
    copy_kernel<<<dim3(16384), dim3(256), 0, stream>>>(x, outp);
}

// Round 2
// 452.886 us; speedup vs baseline: 1.5612x; 1.5612x over previous
//
#include <hip/hip_runtime.h>
#include <math.h>

#define BB 8
#define CH 96
#define HH 256
#define WW 256
#define PD 64      // PDIM
#define NBASE 8
#define KK 13
#define SK 3
#define HID 32

#define PLANE 65536  // 256*256

// ---------------- K1: pooled mean over H,W for first 64 channels ----------------
__global__ __launch_bounds__(256) void pool_kernel(const float* __restrict__ x,
                                                   float* __restrict__ pooled) {
    int blk = blockIdx.x;            // b*64 + c
    int b = blk >> 6, c = blk & 63;
    const float4* p4 = (const float4*)(x + (size_t)(b * CH + c) * PLANE);
    int t = threadIdx.x;
    float s = 0.f;
#pragma unroll
    for (int i = 0; i < 64; ++i) {
        float4 v = p4[t + (i << 8)];
        s += v.x + v.y + v.z + v.w;
    }
#pragma unroll
    for (int off = 32; off; off >>= 1) s += __shfl_down(s, off, 64);
    __shared__ float ls[4];
    if ((t & 63) == 0) ls[t >> 6] = s;
    __syncthreads();
    if (t == 0) pooled[blk] = (ls[0] + ls[1] + ls[2] + ls[3]) * (1.f / 65536.f);
}

// ---------------- K2: all tiny MLPs + softmaxes + kernel composition ----------------
__global__ __launch_bounds__(256) void mlp_kernel(
    const float* __restrict__ pooled, const float* __restrict__ lk_bases,
    const float* __restrict__ rw1, const float* __restrict__ rb1,
    const float* __restrict__ rw2, const float* __restrict__ rb2,
    const float* __restrict__ sw1, const float* __restrict__ sb1,
    const float* __restrict__ sw2, const float* __restrict__ sb2,
    const float* __restrict__ gw1, const float* __restrict__ gb1,
    const float* __restrict__ gw2, const float* __restrict__ gb2,
    float* __restrict__ composed, float* __restrict__ dynk,
    float* __restrict__ glk, float* __restrict__ gdyn) {
    int b = blockIdx.x;
    int t = threadIdx.x;
    __shared__ float pl[64];
    __shared__ float h[3][HID];
    __shared__ float ro[PD * NBASE];
    __shared__ float go[2 * PD];
    __shared__ float rw[PD][NBASE];

    if (t < 64) pl[t] = pooled[b * 64 + t];
    __syncthreads();

    if (t < 96) {
        int m = t >> 5, u = t & 31;
        const float* w1 = (m == 0) ? rw1 : ((m == 1) ? sw1 : gw1);
        const float* b1 = (m == 0) ? rb1 : ((m == 1) ? sb1 : gb1);
        float a = b1[u];
#pragma unroll
        for (int i = 0; i < 64; ++i) a += w1[u * 64 + i] * pl[i];
        // exact gelu: x * 0.5 * (1 + erf(x/sqrt(2)))
        h[m][u] = a * 0.5f * (1.f + erff(a * 0.70710678118654752f));
    }
    __syncthreads();

    for (int o = t; o < PD * NBASE; o += 256) {
        float a = rb2[o];
#pragma unroll
        for (int i = 0; i < HID; ++i) a += rw2[o * HID + i] * h[0][i];
        ro[o] = a;
    }
    for (int o = t; o < PD * SK * SK; o += 256) {
        float a = sb2[o];
#pragma unroll
        for (int i = 0; i < HID; ++i) a += sw2[o * HID + i] * h[1][i];
        dynk[b * PD * SK * SK + o] = a;
    }
    if (t < 2 * PD) {
        float a = gb2[t];
#pragma unroll
        for (int i = 0; i < HID; ++i) a += gw2[t * HID + i] * h[2][i];
        go[t] = a;
    }
    __syncthreads();

    if (t < 64) {
        // softmax over NB for rw
        float m = -1e30f;
#pragma unroll
        for (int n = 0; n < NBASE; ++n) m = fmaxf(m, ro[t * NBASE + n]);
        float e[NBASE], s = 0.f;
#pragma unroll
        for (int n = 0; n < NBASE; ++n) { e[n] = expf(ro[t * NBASE + n] - m); s += e[n]; }
        float inv = 1.f / s;
#pragma unroll
        for (int n = 0; n < NBASE; ++n) rw[t][n] = e[n] * inv;
        // gate softmax over the 2 experts
        float a0 = go[t], a1 = go[64 + t];
        float mm = fmaxf(a0, a1);
        float e0 = expf(a0 - mm), e1 = expf(a1 - mm);
        float gi = 1.f / (e0 + e1);
        glk[b * 64 + t] = e0 * gi;
        gdyn[b * 64 + t] = e1 * gi;
    }
    __syncthreads();

    for (int idx = t; idx < 64 * KK * KK; idx += 256) {
        int c = idx / (KK * KK);
        int j = idx - c * (KK * KK);
        float a = 0.f;
#pragma unroll
        for (int n = 0; n < NBASE; ++n) a += rw[c][n] * lk_bases[n * KK * KK + j];
        composed[(size_t)(b * 64 + c) * (KK * KK) + j] = a;
    }
}

// ---------------- K3: fused depthwise 13x13 + 3x3 + gating; writes fused into d_out y1 slots ----------------
#define TH 32
#define TW 64
#define TROWS 44     // TH + 12
// TSTR=84: row stride mod 32 = 20, so 20*r mod 32 covers all 8 distinct
// 4-aligned bank slots for r=0..7; combined with wg*8 the 64 lanes' b128
// reads spread uniformly over all 32 banks -> conflict-free (min 8 phases).
#define TSTR 84

__global__ __launch_bounds__(256) void conv_kernel(
    const float* __restrict__ x, const float* __restrict__ composed,
    const float* __restrict__ dynk, const float* __restrict__ glk,
    const float* __restrict__ gdyn, float* __restrict__ outp) {
    int tx = blockIdx.x;              // 32 tiles: 4 W-tiles x 8 H-tiles
    int wt = tx & 3, ht = tx >> 2;
    int c = blockIdx.y, b = blockIdx.z;
    int h0 = ht * TH, w0 = wt * TW;
    int t = threadIdx.x;

    __shared__ __align__(16) float tile[TROWS * TSTR];
    __shared__ __align__(16) float kl[13 * 16];
    __shared__ float dk[9];

    const float* xp = x + (size_t)(b * CH + c) * PLANE;
    for (int idx = t; idx < TROWS * TSTR; idx += 256) {
        int rr = idx / TSTR, cc = idx - rr * TSTR;
        int gh = h0 - 6 + rr, gw = w0 - 6 + cc;
        float v = 0.f;
        if (gh >= 0 && gh < HH && gw >= 0 && gw < WW) v = xp[gh * WW + gw];
        tile[idx] = v;
    }
    if (t < 169) {
        int dy = t / 13, dw = t - dy * 13;
        kl[dy * 16 + dw] = composed[(size_t)(b * 64 + c) * 169 + t];
    }
    if (t >= 192 && t < 201) dk[t - 192] = dynk[b * PD * 9 + c * 9 + (t - 192)];
    __syncthreads();

    int wg = t & 7;        // 8 w-groups of 8 pixels
    int r  = t >> 3;       // 32 rows

    float dkr[9];
#pragma unroll
    for (int i = 0; i < 9; ++i) dkr[i] = dk[i];   // broadcast, no conflict

    float acc[8]  = {0, 0, 0, 0, 0, 0, 0, 0};
    float acc2[8] = {0, 0, 0, 0, 0, 0, 0, 0};

#pragma unroll
    for (int dy = 0; dy < 13; ++dy) {
        const float* xr = &tile[(r + dy) * TSTR + wg * 8];
        float kv[16];
        *(float4*)&kv[0] = *(const float4*)&kl[dy * 16];
        *(float4*)&kv[4] = *(const float4*)&kl[dy * 16 + 4];
        *(float4*)&kv[8] = *(const float4*)&kl[dy * 16 + 8];
        kv[12] = kl[dy * 16 + 12];
        float xv[20] __attribute__((aligned(16)));
        *(float4*)&xv[0]  = *(const float4*)&xr[0];
        *(float4*)&xv[4]  = *(const float4*)&xr[4];
        *(float4*)&xv[8]  = *(const float4*)&xr[8];
        *(float4*)&xv[12] = *(const float4*)&xr[12];
        *(float4*)&xv[16] = *(const float4*)&xr[16];
#pragma unroll
        for (int dw = 0; dw < 13; ++dw)
#pragma unroll
            for (int j = 0; j < 8; ++j)
                acc[j] = fmaf(kv[dw], xv[dw + j], acc[j]);
        // 3x3 dynamic kernel rides on rows dy=5,6,7 (cols 5..14 of xv) -> zero
        // extra LDS traffic
        if (dy >= 5 && dy < 8) {
            const int ky = dy - 5;
#pragma unroll
            for (int dw2 = 0; dw2 < 3; ++dw2) {
                float kvd = dkr[ky * 3 + dw2];
#pragma unroll
                for (int j = 0; j < 8; ++j)
                    acc2[j] = fmaf(kvd, xv[5 + j + dw2], acc2[j]);
            }
        }
    }

    float gl = glk[b * 64 + c], gd = gdyn[b * 64 + c];
    float* op = outp + (size_t)(b * CH + c) * PLANE + (h0 + r) * WW + (w0 + wg * 8);
    float4 o0, o1;
    o0.x = gl * acc[0] + gd * acc2[0];
    o0.y = gl * acc[1] + gd * acc2[1];
    o0.z = gl * acc[2] + gd * acc2[2];
    o0.w = gl * acc[3] + gd * acc2[3];
    o1.x = gl * acc[4] + gd * acc2[4];
    o1.y = gl * acc[5] + gd * acc2[5];
    o1.z = gl * acc[6] + gd * acc2[6];
    o1.w = gl * acc[7] + gd * acc2[7];
    *(float4*)&op[0] = o0;
    *(float4*)&op[4] = o1;
}

// ---------------- K4: 64x64 pointwise + bias + residual, in-place on d_out y1 slots ----------------
__global__ __launch_bounds__(256) void pointwise_kernel(
    const float* __restrict__ x, const float* __restrict__ fw,
    const float* __restrict__ fb, float* __restrict__ outp) {
    int b = blockIdx.y;
    int px = blockIdx.x * 256 + threadIdx.x;   // 0..65535
    const size_t bb = (size_t)b * CH * PLANE;

    float f[64];
#pragma unroll
    for (int c = 0; c < 64; ++c) f[c] = outp[bb + (size_t)c * PLANE + px];

    for (int o = 0; o < 64; ++o) {
        float a = fb[o];
#pragma unroll
        for (int c = 0; c < 64; ++c) a = fmaf(fw[o * 64 + c], f[c], a);
        outp[bb + (size_t)o * PLANE + px] = a + x[bb + (size_t)o * PLANE + px];
    }
}

// ---------------- K5: pass-through copy of channels 64..95 ----------------
__global__ __launch_bounds__(256) void copy_kernel(const float* __restrict__ x,
                                                   float* __restrict__ outp) {
    size_t i = (size_t)blockIdx.x * 256 + threadIdx.x;  // over 4,194,304 float4
    int b = (int)(i >> 19);                             // 524288 float4 per batch
    size_t off = i & 524287;
    const float4* s = (const float4*)(x + ((size_t)b * CH + 64) * PLANE) + off;
    float4* d = (float4*)(outp + ((size_t)b * CH + 64) * PLANE) + off;
    *d = *s;
}

extern "C" void kernel_launch(void* const* d_in, const int* in_sizes, int n_in,
                              void* d_out, int out_size, void* d_ws, size_t ws_size,
                              hipStream_t stream) {
    const float* x        = (const float*)d_in[0];
    const float* lk_bases = (const float*)d_in[1];
    const float* rw1      = (const float*)d_in[2];
    const float* rb1      = (const float*)d_in[3];
    const float* rw2      = (const float*)d_in[4];
    const float* rb2      = (const float*)d_in[5];
    const float* sw1      = (const float*)d_in[6];
    const float* sb1      = (const float*)d_in[7];
    const float* sw2      = (const float*)d_in[8];
    const float* sb2      = (const float*)d_in[9];
    const float* gw1      = (const float*)d_in[10];
    const float* gb1      = (const float*)d_in[11];
    const float* gw2      = (const float*)d_in[12];
    const float* gb2      = (const float*)d_in[13];
    const float* fw       = (const float*)d_in[14];
    const float* fb       = (const float*)d_in[15];
    float* outp = (float*)d_out;

    float* wsf      = (float*)d_ws;
    float* pooled   = wsf;                 // 512
    float* composed = wsf + 512;           // 86528
    float* dynk     = wsf + 87040;         // 4608
    float* glk      = wsf + 91648;         // 512
    float* gdyn     = wsf + 92160;         // 512

    pool_kernel<<<dim3(512), dim3(256), 0, stream>>>(x, pooled);
    mlp_kernel<<<dim3(8), dim3(256), 0, stream>>>(pooled, lk_bases,
        rw1, rb1, rw2, rb2, sw1, sb1, sw2, sb2, gw1, gb1, gw2, gb2,
        composed, dynk, glk, gdyn);
    conv_kernel<<<dim3(32, 64, 8), dim3(256), 0, stream>>>(x, composed, dynk, glk, gdyn, outp);
    pointwise_kernel<<<dim3(256, 8), dim3(256), 0, stream>>>(x, fw, fb, outp);
    copy_kernel<<<dim3(16384), dim3(256), 0, stream>>>(x, outp);
}

// Round 3
// 385.476 us; speedup vs baseline: 1.8342x; 1.1749x over previous
//
#include <hip/hip_runtime.h>
#include <math.h>

#define CH 96
#define HH 256
#define WW 256
#define PD 64      // PDIM
#define NBASE 8
#define KK 13
#define HID 32
#define PLANE 65536  // 256*256

// ---------------- K1: partial pooled sums (4 partials per (b,c)) ----------------
__global__ __launch_bounds__(256) void pool_kernel(const float* __restrict__ x,
                                                   float* __restrict__ partial) {
    int blk = blockIdx.x;            // ((b*64+c)*4)+q
    int q = blk & 3, c = (blk >> 2) & 63, b = blk >> 8;
    const float4* p4 = (const float4*)(x + (size_t)(b * CH + c) * PLANE) + q * 4096;
    int t = threadIdx.x;
    float s = 0.f;
#pragma unroll
    for (int i = 0; i < 16; ++i) {
        float4 v = p4[t + (i << 8)];
        s += v.x + v.y + v.z + v.w;
    }
#pragma unroll
    for (int off = 32; off; off >>= 1) s += __shfl_down(s, off, 64);
    __shared__ float ls[4];
    if ((t & 63) == 0) ls[t >> 6] = s;
    __syncthreads();
    if (t == 0) partial[blk] = ls[0] + ls[1] + ls[2] + ls[3];
}

// ---------------- K2: tiny MLPs + softmaxes + merged, pre-gated 13x13 kernel ----------------
__global__ __launch_bounds__(256) void mlp_kernel(
    const float* __restrict__ partial, const float* __restrict__ lk_bases,
    const float* __restrict__ rw1, const float* __restrict__ rb1,
    const float* __restrict__ rw2, const float* __restrict__ rb2,
    const float* __restrict__ sw1, const float* __restrict__ sb1,
    const float* __restrict__ sw2, const float* __restrict__ sb2,
    const float* __restrict__ gw1, const float* __restrict__ gb1,
    const float* __restrict__ gw2, const float* __restrict__ gb2,
    float* __restrict__ keff) {
    int b = blockIdx.x;
    int t = threadIdx.x;
    __shared__ float pl[64];
    __shared__ float h[3][HID];
    __shared__ float ro[PD * NBASE];
    __shared__ float go[2 * PD];
    __shared__ float rw[PD][NBASE];
    __shared__ float dk_s[PD * 9];
    __shared__ float gl_s[PD], gd_s[PD];

    if (t < 64) {
        const float* pp = &partial[(b * 64 + t) * 4];
        pl[t] = (pp[0] + pp[1] + pp[2] + pp[3]) * (1.f / 65536.f);
    }
    __syncthreads();

    if (t < 96) {
        int m = t >> 5, u = t & 31;
        const float* w1 = (m == 0) ? rw1 : ((m == 1) ? sw1 : gw1);
        const float* b1 = (m == 0) ? rb1 : ((m == 1) ? sb1 : gb1);
        float a = b1[u];
#pragma unroll
        for (int i = 0; i < 64; ++i) a += w1[u * 64 + i] * pl[i];
        h[m][u] = a * 0.5f * (1.f + erff(a * 0.70710678118654752f));
    }
    __syncthreads();

    for (int o = t; o < PD * NBASE; o += 256) {
        float a = rb2[o];
#pragma unroll
        for (int i = 0; i < HID; ++i) a += rw2[o * HID + i] * h[0][i];
        ro[o] = a;
    }
    for (int o = t; o < PD * 9; o += 256) {
        float a = sb2[o];
#pragma unroll
        for (int i = 0; i < HID; ++i) a += sw2[o * HID + i] * h[1][i];
        dk_s[o] = a;
    }
    if (t < 2 * PD) {
        float a = gb2[t];
#pragma unroll
        for (int i = 0; i < HID; ++i) a += gw2[t * HID + i] * h[2][i];
        go[t] = a;
    }
    __syncthreads();

    if (t < 64) {
        float m = -1e30f;
#pragma unroll
        for (int n = 0; n < NBASE; ++n) m = fmaxf(m, ro[t * NBASE + n]);
        float e[NBASE], s = 0.f;
#pragma unroll
        for (int n = 0; n < NBASE; ++n) { e[n] = expf(ro[t * NBASE + n] - m); s += e[n]; }
        float inv = 1.f / s;
#pragma unroll
        for (int n = 0; n < NBASE; ++n) rw[t][n] = e[n] * inv;
        float a0 = go[t], a1 = go[64 + t];
        float mm = fmaxf(a0, a1);
        float e0 = expf(a0 - mm), e1 = expf(a1 - mm);
        float gi = 1.f / (e0 + e1);
        gl_s[t] = e0 * gi;
        gd_s[t] = e1 * gi;
    }
    __syncthreads();

    // keff = gl * (softmax-weighted bases) + gd * pad(dyn 3x3 at center)
    for (int idx = t; idx < 64 * 169; idx += 256) {
        int c = idx / 169;
        int tap = idx - c * 169;
        int dy = tap / 13, dx = tap - dy * 13;
        float a = 0.f;
#pragma unroll
        for (int n = 0; n < NBASE; ++n) a += rw[c][n] * lk_bases[n * 169 + tap];
        a *= gl_s[c];
        if (dy >= 5 && dy < 8 && dx >= 5 && dx < 8)
            a += gd_s[c] * dk_s[c * 9 + (dy - 5) * 3 + (dx - 5)];
        keff[(size_t)(b * 64 + c) * 169 + tap] = a;
    }
}

// ---------------- K3: single merged depthwise 13x13, 4x4 register block ----------------
#define TDIM 64
#define TSTR 76      // 64 + 12, multiple of 4 (b128-aligned)
#define TROWS 76

__global__ __launch_bounds__(256) void conv_kernel(
    const float* __restrict__ x, const float* __restrict__ keff,
    float* __restrict__ outp) {
    int tx = blockIdx.x;              // 16 tiles: 4x4 of 64x64
    int wt = tx & 3, ht = tx >> 2;
    int c = blockIdx.y, b = blockIdx.z;
    int h0 = ht * TDIM, w0 = wt * TDIM;
    int t = threadIdx.x;

    __shared__ __align__(16) float tile[TROWS * TSTR];   // 5776 floats = 23.1 KB

    const float* xp = x + (size_t)(b * CH + c) * PLANE;
    for (int idx = t; idx < TROWS * TSTR; idx += 256) {
        int rr = idx / TSTR, cc = idx - rr * TSTR;
        int gh = h0 - 6 + rr, gw = w0 - 6 + cc;
        float v = 0.f;
        if (gh >= 0 && gh < HH && gw >= 0 && gw < WW) v = xp[gh * WW + gw];
        tile[idx] = v;
    }
    __syncthreads();

    // kernel taps: wave-uniform address -> scalar loads -> SGPRs
    const float* krow = keff + (size_t)(b * 64 + c) * 169;

    int tc = t & 15;   // 16 col-groups of 4 -> lane stride 16B: conflict-free b128
    int tr = t >> 4;   // 16 row-groups of 4 contiguous rows

    float acc[4][4] = {{0.f}};
    float kw[4][13];   // rotating 4-row kernel window (SGPR-resident)

#pragma unroll
    for (int j = 0; j < 16; ++j) {
        const float* xr = &tile[(4 * tr + j) * TSTR + 4 * tc];
        float xv[16];
        *(float4*)&xv[0]  = *(const float4*)&xr[0];
        *(float4*)&xv[4]  = *(const float4*)&xr[4];
        *(float4*)&xv[8]  = *(const float4*)&xr[8];
        *(float4*)&xv[12] = *(const float4*)&xr[12];
        if (j < 13) {
#pragma unroll
            for (int d = 0; d < 13; ++d) kw[j & 3][d] = krow[j * 13 + d];
        }
#pragma unroll
        for (int i = 0; i < 4; ++i) {
            const int dy = j - i;
            if (dy >= 0 && dy < 13) {
#pragma unroll
                for (int dx = 0; dx < 13; ++dx)
#pragma unroll
                    for (int m = 0; m < 4; ++m)
                        acc[i][m] = fmaf(kw[dy & 3][dx], xv[dx + m], acc[i][m]);
            }
        }
    }

    float* op = outp + (size_t)(b * CH + c) * PLANE + (size_t)(h0 + 4 * tr) * WW + (w0 + 4 * tc);
#pragma unroll
    for (int i = 0; i < 4; ++i)
        *(float4*)&op[(size_t)i * WW] = *(float4*)&acc[i][0];
}

// ---------------- K4: 64x64 pointwise + bias + residual (in place) + x2 copy ----------------
__global__ __launch_bounds__(256) void pwcopy_kernel(
    const float* __restrict__ x, const float* __restrict__ fw,
    const float* __restrict__ fb, float* outp) {
    int b = blockIdx.y;
    int px = blockIdx.x * 256 + threadIdx.x;   // 0..65535
    const size_t bb = (size_t)b * CH * PLANE;

    float f[64];
#pragma unroll
    for (int c = 0; c < 64; ++c) f[c] = outp[bb + (size_t)c * PLANE + px];

    for (int o = 0; o < 64; ++o) {
        float a = fb[o];
#pragma unroll
        for (int c2 = 0; c2 < 64; ++c2) a = fmaf(fw[o * 64 + c2], f[c2], a);
        outp[bb + (size_t)o * PLANE + px] = a + x[bb + (size_t)o * PLANE + px];
    }
#pragma unroll
    for (int c = 0; c < 32; ++c) {
        size_t off = bb + (size_t)(64 + c) * PLANE + px;
        outp[off] = x[off];
    }
}

extern "C" void kernel_launch(void* const* d_in, const int* in_sizes, int n_in,
                              void* d_out, int out_size, void* d_ws, size_t ws_size,
                              hipStream_t stream) {
    const float* x        = (const float*)d_in[0];
    const float* lk_bases = (const float*)d_in[1];
    const float* rw1      = (const float*)d_in[2];
    const float* rb1      = (const float*)d_in[3];
    const float* rw2      = (const float*)d_in[4];
    const float* rb2      = (const float*)d_in[5];
    const float* sw1      = (const float*)d_in[6];
    const float* sb1      = (const float*)d_in[7];
    const float* sw2      = (const float*)d_in[8];
    const float* sb2      = (const float*)d_in[9];
    const float* gw1      = (const float*)d_in[10];
    const float* gb1      = (const float*)d_in[11];
    const float* gw2      = (const float*)d_in[12];
    const float* gb2      = (const float*)d_in[13];
    const float* fw       = (const float*)d_in[14];
    const float* fb       = (const float*)d_in[15];
    float* outp = (float*)d_out;

    float* wsf     = (float*)d_ws;
    float* partial = wsf;           // 2048 floats
    float* keff    = wsf + 2048;    // 8*64*169 = 86528 floats

    pool_kernel<<<dim3(2048), dim3(256), 0, stream>>>(x, partial);
    mlp_kernel<<<dim3(8), dim3(256), 0, stream>>>(partial, lk_bases,
        rw1, rb1, rw2, rb2, sw1, sb1, sw2, sb2, gw1, gb1, gw2, gb2, keff);
    conv_kernel<<<dim3(16, 64, 8), dim3(256), 0, stream>>>(x, keff, outp);
    pwcopy_kernel<<<dim3(256, 8), dim3(256), 0, stream>>>(x, fw, fb, outp);
}

// Round 4
// 378.137 us; speedup vs baseline: 1.8698x; 1.0194x over previous
//
#include <hip/hip_runtime.h>
#include <math.h>

#define CH 96
#define HH 256
#define WW 256
#define PD 64      // PDIM
#define NBASE 8
#define KK 13
#define HID 32
#define PLANE 65536  // 256*256

// ---------------- K1: partial pooled sums (4 partials per (b,c)) ----------------
__global__ __launch_bounds__(256) void pool_kernel(const float* __restrict__ x,
                                                   float* __restrict__ partial) {
    int blk = blockIdx.x;            // ((b*64+c)*4)+q
    int q = blk & 3, c = (blk >> 2) & 63, b = blk >> 8;
    const float4* p4 = (const float4*)(x + (size_t)(b * CH + c) * PLANE) + q * 4096;
    int t = threadIdx.x;
    float s = 0.f;
#pragma unroll
    for (int i = 0; i < 16; ++i) {
        float4 v = p4[t + (i << 8)];
        s += v.x + v.y + v.z + v.w;
    }
#pragma unroll
    for (int off = 32; off; off >>= 1) s += __shfl_down(s, off, 64);
    __shared__ float ls[4];
    if ((t & 63) == 0) ls[t >> 6] = s;
    __syncthreads();
    if (t == 0) partial[blk] = ls[0] + ls[1] + ls[2] + ls[3];
}

// ---------------- K2: tiny MLPs + softmaxes + merged pre-gated 13x13 kernel + fw transpose ----------------
__global__ __launch_bounds__(256) void mlp_kernel(
    const float* __restrict__ partial, const float* __restrict__ lk_bases,
    const float* __restrict__ rw1, const float* __restrict__ rb1,
    const float* __restrict__ rw2, const float* __restrict__ rb2,
    const float* __restrict__ sw1, const float* __restrict__ sb1,
    const float* __restrict__ sw2, const float* __restrict__ sb2,
    const float* __restrict__ gw1, const float* __restrict__ gb1,
    const float* __restrict__ gw2, const float* __restrict__ gb2,
    const float* __restrict__ fw,
    float* __restrict__ keff, float* __restrict__ fwT) {
    int b = blockIdx.x;
    int t = threadIdx.x;
    __shared__ float pl[64];
    __shared__ float h[3][HID];
    __shared__ float ro[PD * NBASE];
    __shared__ float go[2 * PD];
    __shared__ float rw[PD][NBASE];
    __shared__ float dk_s[PD * 9];
    __shared__ float gl_s[PD], gd_s[PD];

    // fw transpose (block 0 only; later kernels sync at launch boundary)
    if (b == 0) {
        for (int idx = t; idx < 4096; idx += 256) {
            int o = idx >> 6, c = idx & 63;
            fwT[c * 64 + o] = fw[idx];
        }
    }

    if (t < 64) {
        const float* pp = &partial[(b * 64 + t) * 4];
        pl[t] = (pp[0] + pp[1] + pp[2] + pp[3]) * (1.f / 65536.f);
    }
    __syncthreads();

    if (t < 96) {
        int m = t >> 5, u = t & 31;
        const float* w1 = (m == 0) ? rw1 : ((m == 1) ? sw1 : gw1);
        const float* b1 = (m == 0) ? rb1 : ((m == 1) ? sb1 : gb1);
        float a = b1[u];
#pragma unroll
        for (int i = 0; i < 64; ++i) a += w1[u * 64 + i] * pl[i];
        h[m][u] = a * 0.5f * (1.f + erff(a * 0.70710678118654752f));
    }
    __syncthreads();

    for (int o = t; o < PD * NBASE; o += 256) {
        float a = rb2[o];
#pragma unroll
        for (int i = 0; i < HID; ++i) a += rw2[o * HID + i] * h[0][i];
        ro[o] = a;
    }
    for (int o = t; o < PD * 9; o += 256) {
        float a = sb2[o];
#pragma unroll
        for (int i = 0; i < HID; ++i) a += sw2[o * HID + i] * h[1][i];
        dk_s[o] = a;
    }
    if (t < 2 * PD) {
        float a = gb2[t];
#pragma unroll
        for (int i = 0; i < HID; ++i) a += gw2[t * HID + i] * h[2][i];
        go[t] = a;
    }
    __syncthreads();

    if (t < 64) {
        float m = -1e30f;
#pragma unroll
        for (int n = 0; n < NBASE; ++n) m = fmaxf(m, ro[t * NBASE + n]);
        float e[NBASE], s = 0.f;
#pragma unroll
        for (int n = 0; n < NBASE; ++n) { e[n] = expf(ro[t * NBASE + n] - m); s += e[n]; }
        float inv = 1.f / s;
#pragma unroll
        for (int n = 0; n < NBASE; ++n) rw[t][n] = e[n] * inv;
        float a0 = go[t], a1 = go[64 + t];
        float mm = fmaxf(a0, a1);
        float e0 = expf(a0 - mm), e1 = expf(a1 - mm);
        float gi = 1.f / (e0 + e1);
        gl_s[t] = e0 * gi;
        gd_s[t] = e1 * gi;
    }
    __syncthreads();

    // keff = gl * (softmax-weighted bases) + gd * pad(dyn 3x3 at center)
    for (int idx = t; idx < 64 * 169; idx += 256) {
        int c = idx / 169;
        int tap = idx - c * 169;
        int dy = tap / 13, dx = tap - dy * 13;
        float a = 0.f;
#pragma unroll
        for (int n = 0; n < NBASE; ++n) a += rw[c][n] * lk_bases[n * 169 + tap];
        a *= gl_s[c];
        if (dy >= 5 && dy < 8 && dx >= 5 && dx < 8)
            a += gd_s[c] * dk_s[c * 9 + (dy - 5) * 3 + (dx - 5)];
        keff[(size_t)(b * 64 + c) * 169 + tap] = a;
    }
}

// ---------------- K3: single merged depthwise 13x13, 4x4 register block ----------------
#define TDIM 64
#define TSTR 76      // 64 + 12, multiple of 4 (b128-aligned)
#define TROWS 76

__global__ __launch_bounds__(256) void conv_kernel(
    const float* __restrict__ x, const float* __restrict__ keff,
    float* __restrict__ outp) {
    int tx = blockIdx.x;              // 16 tiles: 4x4 of 64x64
    int wt = tx & 3, ht = tx >> 2;
    int c = blockIdx.y, b = blockIdx.z;
    int h0 = ht * TDIM, w0 = wt * TDIM;
    int t = threadIdx.x;

    __shared__ __align__(16) float tile[TROWS * TSTR];   // 5776 floats = 23.1 KB

    const float* xp = x + (size_t)(b * CH + c) * PLANE;
    for (int idx = t; idx < TROWS * TSTR; idx += 256) {
        int rr = idx / TSTR, cc = idx - rr * TSTR;
        int gh = h0 - 6 + rr, gw = w0 - 6 + cc;
        float v = 0.f;
        if (gh >= 0 && gh < HH && gw >= 0 && gw < WW) v = xp[gh * WW + gw];
        tile[idx] = v;
    }
    __syncthreads();

    // kernel taps: wave-uniform address -> scalar loads -> SGPRs
    const float* krow = keff + (size_t)(b * 64 + c) * 169;

    int tc = t & 15;   // 16 col-groups of 4 -> lane stride 16B
    int tr = t >> 4;   // 16 row-groups of 4 contiguous rows

    float acc[4][4] = {{0.f}};
    float kw[4][13];   // rotating 4-row kernel window (SGPR-resident)

#pragma unroll
    for (int j = 0; j < 16; ++j) {
        const float* xr = &tile[(4 * tr + j) * TSTR + 4 * tc];
        float xv[16];
        *(float4*)&xv[0]  = *(const float4*)&xr[0];
        *(float4*)&xv[4]  = *(const float4*)&xr[4];
        *(float4*)&xv[8]  = *(const float4*)&xr[8];
        *(float4*)&xv[12] = *(const float4*)&xr[12];
        if (j < 13) {
#pragma unroll
            for (int d = 0; d < 13; ++d) kw[j & 3][d] = krow[j * 13 + d];
        }
#pragma unroll
        for (int i = 0; i < 4; ++i) {
            const int dy = j - i;
            if (dy >= 0 && dy < 13) {
#pragma unroll
                for (int dx = 0; dx < 13; ++dx)
#pragma unroll
                    for (int m = 0; m < 4; ++m)
                        acc[i][m] = fmaf(kw[dy & 3][dx], xv[dx + m], acc[i][m]);
            }
        }
    }

    float* op = outp + (size_t)(b * CH + c) * PLANE + (size_t)(h0 + 4 * tr) * WW + (w0 + 4 * tc);
#pragma unroll
    for (int i = 0; i < 4; ++i)
        *(float4*)&op[(size_t)i * WW] = *(float4*)&acc[i][0];
}

// ---------------- K4: 64x64 pointwise + bias + residual (in place) + x2 copy ----------------
// acc-streaming: 64 independent accumulators, stream input channels ->
// no dependent FMA chain; weights via contiguous fwT rows -> scalar s_load.
__global__ __launch_bounds__(256) void pwcopy_kernel(
    const float* __restrict__ x, const float* __restrict__ fwT,
    const float* __restrict__ fb, float* outp) {
    int b = blockIdx.y;
    int px = blockIdx.x * 256 + threadIdx.x;   // 0..65535
    const size_t bb = (size_t)b * CH * PLANE;

    float acc[64];
#pragma unroll
    for (int o = 0; o < 64; ++o) acc[o] = fb[o];

#pragma unroll 8
    for (int c = 0; c < 64; ++c) {
        float v = outp[bb + (size_t)c * PLANE + px];
        const float* w = fwT + c * 64;
#pragma unroll
        for (int o = 0; o < 64; ++o) acc[o] = fmaf(w[o], v, acc[o]);
    }

#pragma unroll 8
    for (int o = 0; o < 64; ++o) {
        size_t off = bb + (size_t)o * PLANE + px;
        outp[off] = acc[o] + x[off];
    }
#pragma unroll 8
    for (int c = 0; c < 32; ++c) {
        size_t off = bb + (size_t)(64 + c) * PLANE + px;
        outp[off] = x[off];
    }
}

extern "C" void kernel_launch(void* const* d_in, const int* in_sizes, int n_in,
                              void* d_out, int out_size, void* d_ws, size_t ws_size,
                              hipStream_t stream) {
    const float* x        = (const float*)d_in[0];
    const float* lk_bases = (const float*)d_in[1];
    const float* rw1      = (const float*)d_in[2];
    const float* rb1      = (const float*)d_in[3];
    const float* rw2      = (const float*)d_in[4];
    const float* rb2      = (const float*)d_in[5];
    const float* sw1      = (const float*)d_in[6];
    const float* sb1      = (const float*)d_in[7];
    const float* sw2      = (const float*)d_in[8];
    const float* sb2      = (const float*)d_in[9];
    const float* gw1      = (const float*)d_in[10];
    const float* gb1      = (const float*)d_in[11];
    const float* gw2      = (const float*)d_in[12];
    const float* gb2      = (const float*)d_in[13];
    const float* fw       = (const float*)d_in[14];
    const float* fb       = (const float*)d_in[15];
    float* outp = (float*)d_out;

    float* wsf     = (float*)d_ws;
    float* partial = wsf;            // 2048 floats
    float* keff    = wsf + 2048;     // 8*64*169 = 86528 floats
    float* fwT     = wsf + 88576;    // 4096 floats

    pool_kernel<<<dim3(2048), dim3(256), 0, stream>>>(x, partial);
    mlp_kernel<<<dim3(8), dim3(256), 0, stream>>>(partial, lk_bases,
        rw1, rb1, rw2, rb2, sw1, sb1, sw2, sb2, gw1, gb1, gw2, gb2, fw, keff, fwT);
    conv_kernel<<<dim3(16, 64, 8), dim3(256), 0, stream>>>(x, keff, outp);
    pwcopy_kernel<<<dim3(256, 8), dim3(256), 0, stream>>>(x, fwT, fb, outp);
}

// Round 5
// 361.389 us; speedup vs baseline: 1.9565x; 1.0463x over previous
//
#include <hip/hip_runtime.h>
#include <math.h>

#define CH 96
#define HH 256
#define WW 256
#define PD 64      // PDIM
#define NBASE 8
#define KK 13
#define HID 32
#define PLANE 65536  // 256*256

typedef float f32x4 __attribute__((ext_vector_type(4)));
typedef short s16x8 __attribute__((ext_vector_type(8)));

__device__ inline ushort f2bf(float f) {
    uint u = __float_as_uint(f);
    u += 0x7fff + ((u >> 16) & 1);   // round-to-nearest-even
    return (ushort)(u >> 16);
}

// ---------------- K1: partial pooled sums (4 partials per (b,c)) ----------------
__global__ __launch_bounds__(256) void pool_kernel(const float* __restrict__ x,
                                                   float* __restrict__ partial) {
    int blk = blockIdx.x;            // ((b*64+c)*4)+q
    int q = blk & 3, c = (blk >> 2) & 63, b = blk >> 8;
    const float4* p4 = (const float4*)(x + (size_t)(b * CH + c) * PLANE) + q * 4096;
    int t = threadIdx.x;
    float s = 0.f;
#pragma unroll
    for (int i = 0; i < 16; ++i) {
        float4 v = p4[t + (i << 8)];
        s += v.x + v.y + v.z + v.w;
    }
#pragma unroll
    for (int off = 32; off; off >>= 1) s += __shfl_down(s, off, 64);
    __shared__ float ls[4];
    if ((t & 63) == 0) ls[t >> 6] = s;
    __syncthreads();
    if (t == 0) partial[blk] = ls[0] + ls[1] + ls[2] + ls[3];
}

// ---------------- K2: tiny MLPs + softmaxes + merged pre-gated 13x13 kernel ----------------
__global__ __launch_bounds__(256) void mlp_kernel(
    const float* __restrict__ partial, const float* __restrict__ lk_bases,
    const float* __restrict__ rw1, const float* __restrict__ rb1,
    const float* __restrict__ rw2, const float* __restrict__ rb2,
    const float* __restrict__ sw1, const float* __restrict__ sb1,
    const float* __restrict__ sw2, const float* __restrict__ sb2,
    const float* __restrict__ gw1, const float* __restrict__ gb1,
    const float* __restrict__ gw2, const float* __restrict__ gb2,
    float* __restrict__ keff) {
    int b = blockIdx.x;
    int t = threadIdx.x;
    __shared__ float pl[64];
    __shared__ float h[3][HID];
    __shared__ float ro[PD * NBASE];
    __shared__ float go[2 * PD];
    __shared__ float rw[PD][NBASE];
    __shared__ float dk_s[PD * 9];
    __shared__ float gl_s[PD], gd_s[PD];

    if (t < 64) {
        const float* pp = &partial[(b * 64 + t) * 4];
        pl[t] = (pp[0] + pp[1] + pp[2] + pp[3]) * (1.f / 65536.f);
    }
    __syncthreads();

    if (t < 96) {
        int m = t >> 5, u = t & 31;
        const float* w1 = (m == 0) ? rw1 : ((m == 1) ? sw1 : gw1);
        const float* b1 = (m == 0) ? rb1 : ((m == 1) ? sb1 : gb1);
        float a = b1[u];
#pragma unroll
        for (int i = 0; i < 64; ++i) a += w1[u * 64 + i] * pl[i];
        h[m][u] = a * 0.5f * (1.f + erff(a * 0.70710678118654752f));
    }
    __syncthreads();

    for (int o = t; o < PD * NBASE; o += 256) {
        float a = rb2[o];
#pragma unroll
        for (int i = 0; i < HID; ++i) a += rw2[o * HID + i] * h[0][i];
        ro[o] = a;
    }
    for (int o = t; o < PD * 9; o += 256) {
        float a = sb2[o];
#pragma unroll
        for (int i = 0; i < HID; ++i) a += sw2[o * HID + i] * h[1][i];
        dk_s[o] = a;
    }
    if (t < 2 * PD) {
        float a = gb2[t];
#pragma unroll
        for (int i = 0; i < HID; ++i) a += gw2[t * HID + i] * h[2][i];
        go[t] = a;
    }
    __syncthreads();

    if (t < 64) {
        float m = -1e30f;
#pragma unroll
        for (int n = 0; n < NBASE; ++n) m = fmaxf(m, ro[t * NBASE + n]);
        float e[NBASE], s = 0.f;
#pragma unroll
        for (int n = 0; n < NBASE; ++n) { e[n] = expf(ro[t * NBASE + n] - m); s += e[n]; }
        float inv = 1.f / s;
#pragma unroll
        for (int n = 0; n < NBASE; ++n) rw[t][n] = e[n] * inv;
        float a0 = go[t], a1 = go[64 + t];
        float mm = fmaxf(a0, a1);
        float e0 = expf(a0 - mm), e1 = expf(a1 - mm);
        float gi = 1.f / (e0 + e1);
        gl_s[t] = e0 * gi;
        gd_s[t] = e1 * gi;
    }
    __syncthreads();

    // keff = gl * (softmax-weighted bases) + gd * pad(dyn 3x3 at center)
    for (int idx = t; idx < 64 * 169; idx += 256) {
        int c = idx / 169;
        int tap = idx - c * 169;
        int dy = tap / 13, dx = tap - dy * 13;
        float a = 0.f;
#pragma unroll
        for (int n = 0; n < NBASE; ++n) a += rw[c][n] * lk_bases[n * 169 + tap];
        a *= gl_s[c];
        if (dy >= 5 && dy < 8 && dx >= 5 && dx < 8)
            a += gd_s[c] * dk_s[c * 9 + (dy - 5) * 3 + (dx - 5)];
        keff[(size_t)(b * 64 + c) * 169 + tap] = a;
    }
}

// ---------------- K3: merged depthwise 13x13, 4x4 register block, bf16 output ----------------
// fused result stored as bf16 into d_out's x2 region (exactly 64ch*PLANE*2B per batch);
// pw_kernel consumes it, then copy_kernel overwrites the region with x2.
#define TDIM 64
#define TSTR 76      // 64 + 12, multiple of 4 (b128-aligned)
#define TROWS 76

__global__ __launch_bounds__(256) void conv_kernel(
    const float* __restrict__ x, const float* __restrict__ keff,
    float* __restrict__ outp) {
    int tx = blockIdx.x;              // 16 tiles: 4x4 of 64x64
    int wt = tx & 3, ht = tx >> 2;
    int c = blockIdx.y, b = blockIdx.z;
    int h0 = ht * TDIM, w0 = wt * TDIM;
    int t = threadIdx.x;

    __shared__ __align__(16) float tile[TROWS * TSTR];   // 5776 floats = 23.1 KB

    const float* xp = x + (size_t)(b * CH + c) * PLANE;
    for (int idx = t; idx < TROWS * TSTR; idx += 256) {
        int rr = idx / TSTR, cc = idx - rr * TSTR;
        int gh = h0 - 6 + rr, gw = w0 - 6 + cc;
        float v = 0.f;
        if (gh >= 0 && gh < HH && gw >= 0 && gw < WW) v = xp[gh * WW + gw];
        tile[idx] = v;
    }
    __syncthreads();

    const float* krow = keff + (size_t)(b * 64 + c) * 169;

    int tc = t & 15;   // 16 col-groups of 4 -> lane stride 16B
    int tr = t >> 4;   // 16 row-groups of 4 contiguous rows

    float acc[4][4] = {{0.f}};
    float kw[4][13];   // rotating 4-row kernel window (SGPR-resident)

#pragma unroll
    for (int j = 0; j < 16; ++j) {
        const float* xr = &tile[(4 * tr + j) * TSTR + 4 * tc];
        float xv[16];
        *(float4*)&xv[0]  = *(const float4*)&xr[0];
        *(float4*)&xv[4]  = *(const float4*)&xr[4];
        *(float4*)&xv[8]  = *(const float4*)&xr[8];
        *(float4*)&xv[12] = *(const float4*)&xr[12];
        if (j < 13) {
#pragma unroll
            for (int d = 0; d < 13; ++d) kw[j & 3][d] = krow[j * 13 + d];
        }
#pragma unroll
        for (int i = 0; i < 4; ++i) {
            const int dy = j - i;
            if (dy >= 0 && dy < 13) {
#pragma unroll
                for (int dx = 0; dx < 13; ++dx)
#pragma unroll
                    for (int m = 0; m < 4; ++m)
                        acc[i][m] = fmaf(kw[dy & 3][dx], xv[dx + m], acc[i][m]);
            }
        }
    }

    // bf16 epilogue into x2 region of this batch
    ushort* fB = (ushort*)(outp + ((size_t)b * CH + 64) * PLANE);
    size_t base = (size_t)c * PLANE + (size_t)(h0 + 4 * tr) * WW + (w0 + 4 * tc);
#pragma unroll
    for (int i = 0; i < 4; ++i) {
        uint2 u;
        u.x = (uint)f2bf(acc[i][0]) | ((uint)f2bf(acc[i][1]) << 16);
        u.y = (uint)f2bf(acc[i][2]) | ((uint)f2bf(acc[i][3]) << 16);
        *(uint2*)&fB[base + (size_t)i * WW] = u;
    }
}

// ---------------- K4: pointwise 64x64 via bf16 MFMA + bias + residual ----------------
// y1[o,px] = sum_c W[o,c] * F[c,px] + fb[o] + x1[o,px]
// A-frag: W[16*ot+(l&15)][32*ks+8*(l>>4)+i]; B-frag: F[32*ks+8*(l>>4)+i][px0+(l&15)]
// D: col=px=(l&15), row=o=(l>>4)*4+reg   (m89-verified mapping)
__global__ __launch_bounds__(256) void pw_kernel(
    const float* __restrict__ x, const float* __restrict__ fw,
    const float* __restrict__ fb, float* outp) {
    int b = blockIdx.y;
    int w = threadIdx.x >> 6;
    int l = threadIdx.x & 63;
    int px0 = blockIdx.x * 256 + w * 64;
    int lr = l & 15;
    int lg = l >> 4;

    const ushort* fBS = (const ushort*)(outp + ((size_t)b * CH + 64) * PLANE);
    const size_t bb = (size_t)b * CH * PLANE;

    // A-frags (W -> bf16), loaded once
    s16x8 wa[4][2];
#pragma unroll
    for (int ot = 0; ot < 4; ++ot)
#pragma unroll
        for (int ks = 0; ks < 2; ++ks) {
            const float* src = fw + (ot * 16 + lr) * 64 + ks * 32 + lg * 8;
            float4 a0 = *(const float4*)(src);
            float4 a1 = *(const float4*)(src + 4);
            s16x8 v;
            v[0] = (short)f2bf(a0.x); v[1] = (short)f2bf(a0.y);
            v[2] = (short)f2bf(a0.z); v[3] = (short)f2bf(a0.w);
            v[4] = (short)f2bf(a1.x); v[5] = (short)f2bf(a1.y);
            v[6] = (short)f2bf(a1.z); v[7] = (short)f2bf(a1.w);
            wa[ot][ks] = v;
        }

#pragma unroll
    for (int pxg = 0; pxg < 4; ++pxg) {
        int px = px0 + pxg * 16 + lr;
        // B-frags from bf16 fused
        s16x8 vb[2];
#pragma unroll
        for (int ks = 0; ks < 2; ++ks) {
            const ushort* src = fBS + (size_t)(ks * 32 + lg * 8) * PLANE + px;
            s16x8 v;
#pragma unroll
            for (int i = 0; i < 8; ++i) v[i] = (short)src[(size_t)i * PLANE];
            vb[ks] = v;
        }
#pragma unroll
        for (int ot = 0; ot < 4; ++ot) {
            f32x4 acc = {0.f, 0.f, 0.f, 0.f};
            acc = __builtin_amdgcn_mfma_f32_16x16x32_bf16(wa[ot][0], vb[0], acc, 0, 0, 0);
            acc = __builtin_amdgcn_mfma_f32_16x16x32_bf16(wa[ot][1], vb[1], acc, 0, 0, 0);
            float4 fbv = *(const float4*)(fb + ot * 16 + lg * 4);
#pragma unroll
            for (int i = 0; i < 4; ++i) {
                int o = ot * 16 + lg * 4 + i;
                size_t off = bb + (size_t)o * PLANE + px;
                outp[off] = acc[i] + ((const float*)&fbv)[i] + x[off];
            }
        }
    }
}

// ---------------- K5: pass-through copy of channels 64..95 (AFTER pw consumed fB) ----------------
__global__ __launch_bounds__(256) void copy_kernel(const float* __restrict__ x,
                                                   float* __restrict__ outp) {
    size_t i = (size_t)blockIdx.x * 256 + threadIdx.x;  // over 4,194,304 float4
    int b = (int)(i >> 19);                             // 524288 float4 per batch
    size_t off = i & 524287;
    const float4* s = (const float4*)(x + ((size_t)b * CH + 64) * PLANE) + off;
    float4* d = (float4*)(outp + ((size_t)b * CH + 64) * PLANE) + off;
    *d = *s;
}

extern "C" void kernel_launch(void* const* d_in, const int* in_sizes, int n_in,
                              void* d_out, int out_size, void* d_ws, size_t ws_size,
                              hipStream_t stream) {
    const float* x        = (const float*)d_in[0];
    const float* lk_bases = (const float*)d_in[1];
    const float* rw1      = (const float*)d_in[2];
    const float* rb1      = (const float*)d_in[3];
    const float* rw2      = (const float*)d_in[4];
    const float* rb2      = (const float*)d_in[5];
    const float* sw1      = (const float*)d_in[6];
    const float* sb1      = (const float*)d_in[7];
    const float* sw2      = (const float*)d_in[8];
    const float* sb2      = (const float*)d_in[9];
    const float* gw1      = (const float*)d_in[10];
    const float* gb1      = (const float*)d_in[11];
    const float* gw2      = (const float*)d_in[12];
    const float* gb2      = (const float*)d_in[13];
    const float* fw       = (const float*)d_in[14];
    const float* fb       = (const float*)d_in[15];
    float* outp = (float*)d_out;

    float* wsf     = (float*)d_ws;
    float* partial = wsf;            // 2048 floats
    float* keff    = wsf + 2048;     // 8*64*169 = 86528 floats

    pool_kernel<<<dim3(2048), dim3(256), 0, stream>>>(x, partial);
    mlp_kernel<<<dim3(8), dim3(256), 0, stream>>>(partial, lk_bases,
        rw1, rb1, rw2, rb2, sw1, sb1, sw2, sb2, gw1, gb1, gw2, gb2, keff);
    conv_kernel<<<dim3(16, 64, 8), dim3(256), 0, stream>>>(x, keff, outp);
    pw_kernel<<<dim3(256, 8), dim3(256), 0, stream>>>(x, fw, fb, outp);
    copy_kernel<<<dim3(16384), dim3(256), 0, stream>>>(x, outp);
}